// Round 3
// baseline (558.011 us; speedup 1.0000x reference)
//
#include <hip/hip_runtime.h>
#include <hip/hip_bf16.h>
#include <stdint.h>

// z_e (32,64,64,64) f32, codebook (512,64) f32.
// d_out (f32): [0..8388607] z_q (B,C,H,W); [8388608] loss; [8388609..] indices as float.
#define NPIX 131072
#define CDIM 64
#define KCODES 512
#define ZQ_SIZE 8388608
#define LOSS_OFF 8388608
#define IDXOUT_OFF 8388609
#define CH_STRIDE 4096
#define B_STRIDE 262144
#define MARGIN 4e-4f
#define BIAS 0.5f

typedef __attribute__((ext_vector_type(8))) short short8v;   // 8 bf16 (4 VGPRs)
typedef __attribute__((ext_vector_type(16))) float f32x16;
typedef __attribute__((ext_vector_type(4))) float f32x4;

// ws layout:
//   0     double loss
//   8     uint   cnt
//   64    float  c2_ref[512]   (pairwise-8 order, matches np.sum)
//   2112  float  c2b[512]      (accurate ||c||^2 + BIAS)
//   4160  ushort cb_hi chunks  [g=0..7][code=0..511][8 bf16]  (65536 B)
//   69696 uint   flagged[NPIX]
#define WS_C2REF 64
#define WS_C2B   2112
#define WS_CBHI  4160
#define WS_FLAG  69696

__device__ __forceinline__ uint32_t f2bf_rne(float v) {
    uint32_t u = __float_as_uint(v);
    return (u + 0x7FFFu + ((u >> 16) & 1u)) >> 16;
}
__device__ __forceinline__ float bf2f(short s) {
    return __uint_as_float(((uint32_t)(unsigned short)s) << 16);
}

__global__ void k0_prep(const float* __restrict__ cb, char* __restrict__ ws) {
#pragma clang fp contract(off)
    int k = threadIdx.x;
    if (k >= KCODES) return;
    const float* cr = cb + (size_t)k * CDIM;
    // reference-order ||c||^2 (numpy pairwise-8)
    float r[8];
    #pragma unroll
    for (int j = 0; j < 8; ++j) r[j] = cr[j] * cr[j];
    #pragma unroll
    for (int t = 1; t < 8; ++t)
        #pragma unroll
        for (int j = 0; j < 8; ++j) r[j] += cr[8 * t + j] * cr[8 * t + j];
    ((float*)(ws + WS_C2REF))[k] = ((r[0] + r[1]) + (r[2] + r[3])) + ((r[4] + r[5]) + (r[6] + r[7]));
    // accurate ||c||^2 + bias for MFMA acc init
    float acc = 0.f;
    #pragma unroll
    for (int i = 0; i < CDIM; ++i) acc = fmaf(cr[i], cr[i], acc);
    ((float*)(ws + WS_C2B))[k] = acc + BIAS;
    // bf16 codebook, k-major 16B chunks: chunk id = g*512 + k holds ch g*8..g*8+7
    unsigned short* hi = (unsigned short*)(ws + WS_CBHI);
    #pragma unroll
    for (int g = 0; g < 8; ++g)
        #pragma unroll
        for (int j = 0; j < 8; ++j)
            hi[((size_t)(g * KCODES + k)) * 8 + j] = (unsigned short)f2bf_rne(cr[g * 8 + j]);
}

__global__ __launch_bounds__(256, 2) void k1_mfma(const float* __restrict__ z_e,
                                                  const float* __restrict__ cb,
                                                  char* __restrict__ ws,
                                                  float* __restrict__ out) {
    extern __shared__ char smem[];   // 65536 B: codebook-hi chunks, linear
    const int tid  = threadIdx.x;
    const int lane = tid & 63;
    const int wave = tid >> 6;
    const int h    = lane >> 5;      // k-half selector
    const int c    = lane & 31;      // pixel column within set

    // stage codebook-hi to LDS (reg-staged, once)
    {
        const uint4* src = (const uint4*)(ws + WS_CBHI);
        uint4* dst = (uint4*)smem;
        #pragma unroll
        for (int i = 0; i < 16; ++i)
            dst[i * 256 + tid] = src[i * 256 + tid];
    }
    __syncthreads();

    const int gwave  = blockIdx.x * 4 + wave;
    const int pbase  = gwave * 64;          // 64 pixels per wave
    const int b      = pbase >> 12;
    const int hwbase = pbase & 4095;
    const float* zb  = z_e + (size_t)b * B_STRIDE;

    // B fragments: (-2z) bf16 hi/lo, layout col=lane&31, k=(lane>>5)*8+j per K16-step
    short8v zh[2][4], zl[2][4];
    #pragma unroll
    for (int t = 0; t < 2; ++t) {
        int hw = hwbase + t * 32 + c;
        #pragma unroll
        for (int s = 0; s < 4; ++s) {
            int ch0 = s * 16 + h * 8;
            short8v vh, vl;
            #pragma unroll
            for (int j = 0; j < 8; ++j) {
                float z  = zb[(size_t)(ch0 + j) * CH_STRIDE + hw];
                float m2z = -2.0f * z;
                uint32_t uh = f2bf_rne(m2z);
                float lo = m2z - __uint_as_float(uh << 16);
                vh[j] = (short)uh;
                vl[j] = (short)f2bf_rne(lo);
            }
            zh[t][s] = vh; zl[t][s] = vl;
        }
    }

    const float* c2bp = (const float*)(ws + WS_C2B);
    uint32_t m1[2] = {0xFFFFFFFFu, 0xFFFFFFFFu};
    uint32_t m2[2] = {0xFFFFFFFFu, 0xFFFFFFFFu};

    for (int t = 0; t < 16; ++t) {          // 16 code tiles of 32
        short8v a[4];
        #pragma unroll
        for (int s = 0; s < 4; ++s) {
            int chunk = (2 * s + h) * KCODES + t * 32 + c;
            a[s] = *(const short8v*)(smem + (size_t)chunk * 16);
        }
        int rbase = t * 32 + 4 * h;
        f32x4 q0 = *(const f32x4*)(c2bp + rbase + 0);
        f32x4 q1 = *(const f32x4*)(c2bp + rbase + 8);
        f32x4 q2 = *(const f32x4*)(c2bp + rbase + 16);
        f32x4 q3 = *(const f32x4*)(c2bp + rbase + 24);

        #pragma unroll
        for (int set = 0; set < 2; ++set) {
            f32x16 acc;
            #pragma unroll
            for (int i = 0; i < 4; ++i) {
                acc[i] = q0[i]; acc[4 + i] = q1[i]; acc[8 + i] = q2[i]; acc[12 + i] = q3[i];
            }
            #pragma unroll
            for (int s = 0; s < 4; ++s)
                acc = __builtin_amdgcn_mfma_f32_32x32x16_bf16(a[s], zh[set][s], acc, 0, 0, 0);
            #pragma unroll
            for (int s = 0; s < 4; ++s)
                acc = __builtin_amdgcn_mfma_f32_32x32x16_bf16(a[s], zl[set][s], acc, 0, 0, 0);
            // packed min-track: u = (score & ~0x1FF) | code  (scores all positive)
            #pragma unroll
            for (int i = 0; i < 16; ++i) {
                uint32_t code = (uint32_t)(t * 32 + 4 * h + (i & 3) + 8 * (i >> 2));
                uint32_t u = (__float_as_uint(acc[i]) & 0xFFFFFE00u) | code;
                uint32_t mx = m1[set] > u ? m1[set] : u;
                m2[set] = m2[set] < mx ? m2[set] : mx;
                m1[set] = m1[set] < u ? m1[set] : u;
            }
        }
    }

    // merge lanes l and l^32 (same pixel column)
    #pragma unroll
    for (int set = 0; set < 2; ++set) {
        uint32_t o1 = (uint32_t)__shfl_xor((int)m1[set], 32);
        uint32_t o2 = (uint32_t)__shfl_xor((int)m2[set], 32);
        uint32_t mx  = m1[set] > o1 ? m1[set] : o1;
        uint32_t mn2 = m2[set] < o2 ? m2[set] : o2;
        m2[set] = mn2 < mx ? mn2 : mx;
        m1[set] = m1[set] < o1 ? m1[set] : o1;
    }

    int  idxv[2]; bool flag[2];
    #pragma unroll
    for (int set = 0; set < 2; ++set) {
        idxv[set] = (int)(m1[set] & 0x1FFu);
        float f1 = __uint_as_float(m1[set] & 0xFFFFFE00u);
        float f2 = __uint_as_float(m2[set] & 0xFFFFFE00u);
        flag[set] = (f2 - f1) < MARGIN;
    }

    // each lane owns one pixel for idx-output/flagging: set = h, col = c
    {
        int p = pbase + h * 32 + c;
        int own_idx  = h ? idxv[1] : idxv[0];
        bool own_flag = h ? flag[1] : flag[0];
        out[IDXOUT_OFF + p] = (float)own_idx;
        if (own_flag) {
            uint32_t slot = atomicAdd((uint32_t*)(ws + 8), 1u);
            ((uint32_t*)(ws + WS_FLAG))[slot] = (uint32_t)p;
        }
    }

    // fused z_q gather + write + loss (unflagged pixels; each lane its 32 channels)
    float lsum = 0.f;
    #pragma unroll
    for (int set = 0; set < 2; ++set) {
        if (!flag[set]) {
            int hw = hwbase + set * 32 + c;
            const float* crow = cb + (size_t)idxv[set] * CDIM;
            float* ob = out + (size_t)b * B_STRIDE + hw;
            #pragma unroll
            for (int s = 0; s < 4; ++s) {
                int ch0 = s * 16 + h * 8;
                f32x4 g0 = *(const f32x4*)(crow + ch0);
                f32x4 g1 = *(const f32x4*)(crow + ch0 + 4);
                #pragma unroll
                for (int j = 0; j < 8; ++j) {
                    float zq = (j < 4) ? g0[j] : g1[j - 4];
                    float zv = -0.5f * (bf2f(zh[set][s][j]) + bf2f(zl[set][s][j]));
                    ob[(size_t)(ch0 + j) * CH_STRIDE] = zq;
                    float d = zq - zv;
                    lsum = fmaf(d, d, lsum);
                }
            }
        }
    }
    double dl = (double)lsum;
    for (int off = 32; off; off >>= 1) dl += __shfl_down(dl, off);
    if (lane == 0) atomicAdd((double*)ws, dl);
}

// exact reference-arithmetic re-resolution for flagged pixels (Round-2-verified math)
__global__ void k2_refine(const float* __restrict__ z_e,
                          const float* __restrict__ cb,
                          char* __restrict__ ws,
                          float* __restrict__ out) {
#pragma clang fp contract(off)
    const uint32_t n = *(const volatile uint32_t*)(ws + 8);
    const float* c2r = (const float*)(ws + WS_C2REF);
    const uint32_t* flagged = (const uint32_t*)(ws + WS_FLAG);
    int gwave  = (blockIdx.x * blockDim.x + threadIdx.x) >> 6;
    int lane   = threadIdx.x & 63;
    int nwaves = (gridDim.x * blockDim.x) >> 6;

    for (uint32_t f = gwave; f < n; f += nwaves) {
        int p  = (int)flagged[f];
        int bb = p >> 12, hw = p & 4095;
        const float* zb = z_e + (size_t)bb * B_STRIDE + hw;
        float z[CDIM];
        #pragma unroll
        for (int i = 0; i < CDIM; ++i) z[i] = zb[(size_t)i * CH_STRIDE];
        float r[8];
        #pragma unroll
        for (int j = 0; j < 8; ++j) r[j] = z[j] * z[j];
        #pragma unroll
        for (int t = 1; t < 8; ++t)
            #pragma unroll
            for (int j = 0; j < 8; ++j) r[j] += z[8 * t + j] * z[8 * t + j];
        float A = ((r[0] + r[1]) + (r[2] + r[3])) + ((r[4] + r[5]) + (r[6] + r[7]));

        float best = 3.4e38f; int bidx = 0x7FFFFFFF;
        #pragma unroll
        for (int j = 0; j < 8; ++j) {
            int k = lane * 8 + j;
            const float* cr = cb + (size_t)k * CDIM;
            float a = 0.f;
            #pragma unroll
            for (int i = 0; i < CDIM; ++i) a = fmaf(z[i], cr[i], a);
            float d = (A - 2.0f * a) + c2r[k];
            if (d < best) { best = d; bidx = k; }
        }
        for (int off = 32; off; off >>= 1) {
            float ob = __shfl_down(best, off);
            int   oi = __shfl_down(bidx, off);
            if (ob < best || (ob == best && oi < bidx)) { best = ob; bidx = oi; }
        }
        bidx = __shfl(bidx, 0);
        if (lane == 0) out[IDXOUT_OFF + p] = (float)bidx;
        float zq = cb[(size_t)bidx * CDIM + lane];
        float zv = zb[(size_t)lane * CH_STRIDE];
        out[(size_t)bb * B_STRIDE + (size_t)lane * CH_STRIDE + hw] = zq;
        float d = zq - zv;
        double dl = (double)(d * d);
        for (int off = 32; off; off >>= 1) dl += __shfl_down(dl, off);
        if (lane == 0) atomicAdd((double*)ws, dl);
    }
}

__global__ void k4_loss(float* __restrict__ out, const double* __restrict__ loss_acc) {
    out[LOSS_OFF] = (float)(1.25 * (*loss_acc) / (double)ZQ_SIZE);
}

extern "C" void kernel_launch(void* const* d_in, const int* in_sizes, int n_in,
                              void* d_out, int out_size, void* d_ws, size_t ws_size,
                              hipStream_t stream) {
    const float* z_e = (const float*)d_in[0];
    const float* cb  = (const float*)d_in[1];
    float* out = (float*)d_out;
    char* ws = (char*)d_ws;

    hipMemsetAsync(d_ws, 0, 64, stream);
    k0_prep<<<1, 512, 0, stream>>>(cb, ws);
    k1_mfma<<<NPIX / 256, 256, 65536, stream>>>(z_e, cb, ws, out);
    k2_refine<<<256, 256, 0, stream>>>(z_e, cb, ws, out);
    k4_loss<<<1, 1, 0, stream>>>(out, (const double*)ws);
}

// Round 6
// 202.495 us; speedup vs baseline: 2.7557x; 2.7557x over previous
//
#include <hip/hip_runtime.h>
#include <hip/hip_bf16.h>
#include <stdint.h>

// z_e (32,64,64,64) f32, codebook (512,64) f32.
// d_out (f32): [0..8388607] z_q (B,C,H,W); [8388608] loss; [8388609..] indices as float.
#define NPIX 131072
#define CDIM 64
#define KCODES 512
#define ZQ_SIZE 8388608
#define LOSS_OFF 8388608
#define IDXOUT_OFF 8388609
#define CH_STRIDE 4096
#define B_STRIDE 262144
#define MARGIN_UNITS 256       // 256 * 2^-22 ~ 6.1e-5 score gap: covers ref f32 grid noise
#define SCALE 4194304.0f       // 2^22
#define BIAS 0.5f

typedef __attribute__((ext_vector_type(8))) short short8v;   // 8 bf16
typedef __attribute__((ext_vector_type(16))) float f32x16;
typedef __attribute__((ext_vector_type(4))) float f32x4;

// ws layout:
//   0       double loss
//   8       uint   cnt
//   64      float  c2_ref[512]   (numpy pairwise-8 order, for refine)
//   2112    float  c2fix[512]    ((||c||^2 + 0.5) * 2^22)
//   4160    ushort cb_hi chunks  [g=0..7][code][8 bf16], scaled 2^11  (65536 B)
//   69696   ushort cb_lo chunks  same layout, residual scaled 2^11    (65536 B)
//   135232  uint   flagged[NPIX]
#define WS_C2REF 64
#define WS_C2FIX 2112
#define WS_CBHI  4160
#define WS_CBLO  69696
#define WS_FLAG  135232

__device__ __forceinline__ uint32_t f2bf_rne(float v) {
    uint32_t u = __float_as_uint(v);
    return (u + 0x7FFFu + ((u >> 16) & 1u)) >> 16;
}
__device__ __forceinline__ float bf2f(short s) {
    return __uint_as_float(((uint32_t)(unsigned short)s) << 16);
}

__global__ void k0_prep(const float* __restrict__ cb, char* __restrict__ ws) {
#pragma clang fp contract(off)
    int k = threadIdx.x;
    if (k >= KCODES) return;
    const float* cr = cb + (size_t)k * CDIM;
    // reference-order ||c||^2 (numpy pairwise-8) for the exact refine pass
    float r[8];
    #pragma unroll
    for (int j = 0; j < 8; ++j) r[j] = cr[j] * cr[j];
    #pragma unroll
    for (int t = 1; t < 8; ++t)
        #pragma unroll
        for (int j = 0; j < 8; ++j) r[j] += cr[8 * t + j] * cr[8 * t + j];
    ((float*)(ws + WS_C2REF))[k] = ((r[0] + r[1]) + (r[2] + r[3])) + ((r[4] + r[5]) + (r[6] + r[7]));
    // accurate ||c||^2 + bias, pre-scaled to fixed-point units
    float acc = 0.f;
    #pragma unroll
    for (int i = 0; i < CDIM; ++i) acc = fmaf(cr[i], cr[i], acc);
    ((float*)(ws + WS_C2FIX))[k] = (acc + BIAS) * SCALE;
    // bf16 codebook split, scaled by 2^11; k-major 16B chunks: chunk = g*512 + k
    unsigned short* hi = (unsigned short*)(ws + WS_CBHI);
    unsigned short* lo = (unsigned short*)(ws + WS_CBLO);
    #pragma unroll
    for (int g = 0; g < 8; ++g)
        #pragma unroll
        for (int j = 0; j < 8; ++j) {
            float cs = cr[g * 8 + j] * 2048.0f;
            uint32_t uh = f2bf_rne(cs);
            float l = cs - bf2f((short)uh);
            size_t o = ((size_t)(g * KCODES + k)) * 8 + j;
            hi[o] = (unsigned short)uh;
            lo[o] = (unsigned short)f2bf_rne(l);
        }
}

__global__ __launch_bounds__(256, 2) void k1_mfma(const float* __restrict__ z_e,
                                                  const float* __restrict__ cb,
                                                  char* __restrict__ ws,
                                                  float* __restrict__ out) {
    extern __shared__ char smem[];   // 65536 B cb_hi chunks + 2048 B c2fix
    const int tid  = threadIdx.x;
    const int lane = tid & 63;
    const int wave = tid >> 6;
    const int h    = lane >> 5;      // k-half selector
    const int c    = lane & 31;      // column (pixel/code) within 32

    {   // stage cb_hi (64KB) + c2fix (2KB) to LDS
        const uint4* src = (const uint4*)(ws + WS_CBHI);
        uint4* dst = (uint4*)smem;
        #pragma unroll
        for (int i = 0; i < 16; ++i)
            dst[i * 256 + tid] = src[i * 256 + tid];
        if (tid < 128)
            ((uint4*)(smem + 65536))[tid] = ((const uint4*)(ws + WS_C2FIX))[tid];
    }
    __syncthreads();

    const int gwave  = blockIdx.x * 4 + wave;
    const int pbase  = gwave * 64;          // 64 pixels per wave
    const int b      = pbase >> 12;
    const int hwbase = pbase & 4095;
    const float* zb  = z_e + (size_t)b * B_STRIDE;

    // B fragments: Z = -4096*z split hi/lo (scaled bf16); col=lane&31, k=(lane>>5)*8+j
    short8v zh[2][4], zl[2][4];
    #pragma unroll
    for (int t = 0; t < 2; ++t) {
        int hw = hwbase + t * 32 + c;
        #pragma unroll
        for (int s = 0; s < 4; ++s) {
            int ch0 = s * 16 + h * 8;
            short8v vh, vl;
            #pragma unroll
            for (int j = 0; j < 8; ++j) {
                float zs = zb[(size_t)(ch0 + j) * CH_STRIDE + hw] * -4096.0f;
                uint32_t uh = f2bf_rne(zs);
                float l = zs - bf2f((short)uh);
                vh[j] = (short)uh;
                vl[j] = (short)f2bf_rne(l);
            }
            zh[t][s] = vh; zl[t][s] = vl;
        }
    }

    const short8v* lo_chunks = (const short8v*)(ws + WS_CBLO);
    const float* c2f = (const float*)(smem + 65536);
    uint32_t m1[2] = {0xFFFFFFFFu, 0xFFFFFFFFu};
    uint32_t m2[2] = {0xFFFFFFFFu, 0xFFFFFFFFu};

    for (int t = 0; t < 16; ++t) {          // 16 code tiles of 32
        short8v a[4], al[4];
        #pragma unroll
        for (int s = 0; s < 4; ++s) {
            int chunk = (2 * s + h) * KCODES + t * 32 + c;
            a[s]  = *(const short8v*)(smem + (size_t)chunk * 16);
            al[s] = lo_chunks[chunk];
        }
        int rbase = t * 32 + 4 * h;
        f32x4 q0 = *(const f32x4*)(c2f + rbase + 0);
        f32x4 q1 = *(const f32x4*)(c2f + rbase + 8);
        f32x4 q2 = *(const f32x4*)(c2f + rbase + 16);
        f32x4 q3 = *(const f32x4*)(c2f + rbase + 24);

        #pragma unroll
        for (int set = 0; set < 2; ++set) {
            f32x16 acc;
            #pragma unroll
            for (int i = 0; i < 4; ++i) {
                acc[i] = q0[i]; acc[4 + i] = q1[i]; acc[8 + i] = q2[i]; acc[12 + i] = q3[i];
            }
            #pragma unroll
            for (int s = 0; s < 4; ++s)
                acc = __builtin_amdgcn_mfma_f32_32x32x16_bf16(a[s], zh[set][s], acc, 0, 0, 0);
            #pragma unroll
            for (int s = 0; s < 4; ++s)
                acc = __builtin_amdgcn_mfma_f32_32x32x16_bf16(a[s], zl[set][s], acc, 0, 0, 0);
            #pragma unroll
            for (int s = 0; s < 4; ++s)
                acc = __builtin_amdgcn_mfma_f32_32x32x16_bf16(al[s], zh[set][s], acc, 0, 0, 0);
            // fixed-point pack: u = ((uint)score_fixed << 9) | code ; min-track m1,m2
            #pragma unroll
            for (int i = 0; i < 16; ++i) {
                uint32_t code = (uint32_t)(t * 32 + 4 * h + (i & 3) + 8 * (i >> 2));
                uint32_t u = (((uint32_t)acc[i]) << 9) | code;
                uint32_t mx = m1[set] > u ? m1[set] : u;
                m2[set] = m2[set] < mx ? m2[set] : mx;
                m1[set] = m1[set] < u ? m1[set] : u;
            }
        }
    }

    // merge lanes l and l^32 (same pixel column)
    #pragma unroll
    for (int set = 0; set < 2; ++set) {
        uint32_t o1 = (uint32_t)__shfl_xor((int)m1[set], 32);
        uint32_t o2 = (uint32_t)__shfl_xor((int)m2[set], 32);
        uint32_t mx  = m1[set] > o1 ? m1[set] : o1;
        uint32_t mn2 = m2[set] < o2 ? m2[set] : o2;
        m2[set] = mn2 < mx ? mn2 : mx;
        m1[set] = m1[set] < o1 ? m1[set] : o1;
    }

    int  idxv[2]; bool flag[2];
    #pragma unroll
    for (int set = 0; set < 2; ++set) {
        idxv[set] = (int)(m1[set] & 0x1FFu);
        int gap = (int)((m2[set] >> 9) - (m1[set] >> 9));
        flag[set] = gap < MARGIN_UNITS;
    }

    {   // each lane owns one pixel for idx output / flagging
        int p = pbase + h * 32 + c;
        int own_idx   = h ? idxv[1] : idxv[0];
        bool own_flag = h ? flag[1] : flag[0];
        out[IDXOUT_OFF + p] = (float)own_idx;
        if (own_flag) {
            uint32_t slot = atomicAdd((uint32_t*)(ws + 8), 1u);
            ((uint32_t*)(ws + WS_FLAG))[slot] = (uint32_t)p;
        }
    }

    // fused z_q gather + write + loss for unflagged pixels
    float lsum = 0.f;
    #pragma unroll
    for (int set = 0; set < 2; ++set) {
        if (!flag[set]) {
            int hw = hwbase + set * 32 + c;
            const float* crow = cb + (size_t)idxv[set] * CDIM;
            float* ob = out + (size_t)b * B_STRIDE + hw;
            #pragma unroll
            for (int s = 0; s < 4; ++s) {
                int ch0 = s * 16 + h * 8;
                f32x4 g0 = *(const f32x4*)(crow + ch0);
                f32x4 g1 = *(const f32x4*)(crow + ch0 + 4);
                #pragma unroll
                for (int j = 0; j < 8; ++j) {
                    float zq = (j < 4) ? g0[j] : g1[j - 4];
                    float zv = (bf2f(zh[set][s][j]) + bf2f(zl[set][s][j])) * -2.44140625e-4f;
                    ob[(size_t)(ch0 + j) * CH_STRIDE] = zq;
                    float d = zq - zv;
                    lsum = fmaf(d, d, lsum);
                }
            }
        }
    }
    double dl = (double)lsum;
    for (int off = 32; off; off >>= 1) dl += __shfl_down(dl, off);
    if (lane == 0) atomicAdd((double*)ws, dl);
}

// exact reference-arithmetic re-resolution for flagged pixels (Round-2-verified math)
__global__ void k2_refine(const float* __restrict__ z_e,
                          const float* __restrict__ cb,
                          char* __restrict__ ws,
                          float* __restrict__ out) {
#pragma clang fp contract(off)
    const uint32_t n = *(const volatile uint32_t*)(ws + 8);
    const float* c2r = (const float*)(ws + WS_C2REF);
    const uint32_t* flagged = (const uint32_t*)(ws + WS_FLAG);
    int gwave  = (blockIdx.x * blockDim.x + threadIdx.x) >> 6;
    int lane   = threadIdx.x & 63;
    int nwaves = (gridDim.x * blockDim.x) >> 6;

    for (uint32_t f = gwave; f < n; f += nwaves) {
        int p  = (int)flagged[f];
        int bb = p >> 12, hw = p & 4095;
        const float* zb = z_e + (size_t)bb * B_STRIDE + hw;
        float z[CDIM];
        #pragma unroll
        for (int i = 0; i < CDIM; ++i) z[i] = zb[(size_t)i * CH_STRIDE];
        float r[8];
        #pragma unroll
        for (int j = 0; j < 8; ++j) r[j] = z[j] * z[j];
        #pragma unroll
        for (int t = 1; t < 8; ++t)
            #pragma unroll
            for (int j = 0; j < 8; ++j) r[j] += z[8 * t + j] * z[8 * t + j];
        float A = ((r[0] + r[1]) + (r[2] + r[3])) + ((r[4] + r[5]) + (r[6] + r[7]));

        float best = 3.4e38f; int bidx = 0x7FFFFFFF;
        #pragma unroll
        for (int j = 0; j < 8; ++j) {
            int k = lane * 8 + j;
            const float* cr = cb + (size_t)k * CDIM;
            float a = 0.f;
            #pragma unroll
            for (int i = 0; i < CDIM; ++i) a = fmaf(z[i], cr[i], a);
            float d = (A - 2.0f * a) + c2r[k];
            if (d < best) { best = d; bidx = k; }
        }
        for (int off = 32; off; off >>= 1) {
            float ob = __shfl_down(best, off);
            int   oi = __shfl_down(bidx, off);
            if (ob < best || (ob == best && oi < bidx)) { best = ob; bidx = oi; }
        }
        bidx = __shfl(bidx, 0);
        if (lane == 0) out[IDXOUT_OFF + p] = (float)bidx;
        float zq = cb[(size_t)bidx * CDIM + lane];
        float zv = zb[(size_t)lane * CH_STRIDE];
        out[(size_t)bb * B_STRIDE + (size_t)lane * CH_STRIDE + hw] = zq;
        float d = zq - zv;
        double dl = (double)(d * d);
        for (int off = 32; off; off >>= 1) dl += __shfl_down(dl, off);
        if (lane == 0) atomicAdd((double*)ws, dl);
    }
}

__global__ void k4_loss(float* __restrict__ out, const double* __restrict__ loss_acc) {
    out[LOSS_OFF] = (float)(1.25 * (*loss_acc) / (double)ZQ_SIZE);
}

extern "C" void kernel_launch(void* const* d_in, const int* in_sizes, int n_in,
                              void* d_out, int out_size, void* d_ws, size_t ws_size,
                              hipStream_t stream) {
    const float* z_e = (const float*)d_in[0];
    const float* cb  = (const float*)d_in[1];
    float* out = (float*)d_out;
    char* ws = (char*)d_ws;

    hipMemsetAsync(d_ws, 0, 64, stream);
    k0_prep<<<1, 512, 0, stream>>>(cb, ws);
    k1_mfma<<<NPIX / 256, 256, 67584, stream>>>(z_e, cb, ws, out);
    k2_refine<<<512, 256, 0, stream>>>(z_e, cb, ws, out);
    k4_loss<<<1, 1, 0, stream>>>(out, (const double*)ws);
}

// Round 7
// 202.354 us; speedup vs baseline: 2.7576x; 1.0007x over previous
//
#include <hip/hip_runtime.h>
#include <hip/hip_bf16.h>
#include <stdint.h>

// z_e (32,64,64,64) f32, codebook (512,64) f32.
// d_out (f32): [0..8388607] z_q (B,C,H,W); [8388608] loss; [8388609..] indices as float.
#define NPIX 131072
#define CDIM 64
#define KCODES 512
#define ZQ_SIZE 8388608
#define LOSS_OFF 8388608
#define IDXOUT_OFF 8388609
#define CH_STRIDE 4096
#define B_STRIDE 262144
#define MARGIN_UNITS 256       // 256 * 2^-22 ~ 6.1e-5 score gap: covers ref f32 grid noise
#define SCALE 4194304.0f       // 2^22
#define BIAS 0.5f

typedef __attribute__((ext_vector_type(8))) short short8v;   // 8 bf16
typedef __attribute__((ext_vector_type(16))) float f32x16;
typedef __attribute__((ext_vector_type(4))) float f32x4;

// ws layout:
//   0       double loss
//   8       uint   cnt
//   64      float  c2_ref[512]   (numpy pairwise-8 order, for refine)
//   2112    float  c2fix[512]    ((||c||^2 + 0.5) * 2^22)
//   4160    ushort cb_hi chunks  [g=0..7][code][8 bf16], scaled 2^11  (65536 B)
//   69696   ushort cb_lo chunks  same layout, residual scaled 2^11    (65536 B)
//   135232  uint   flagged[NPIX]                                      (524288 B)
//   659520  float  zstash[cap][64]  exact z for flagged slots < cap
#define WS_C2REF 64
#define WS_C2FIX 2112
#define WS_CBHI  4160
#define WS_CBLO  69696
#define WS_FLAG  135232
#define WS_ZSTASH 659520

__device__ __forceinline__ uint32_t f2bf_rne(float v) {
    uint32_t u = __float_as_uint(v);
    return (u + 0x7FFFu + ((u >> 16) & 1u)) >> 16;
}
__device__ __forceinline__ float bf2f(short s) {
    return __uint_as_float(((uint32_t)(unsigned short)s) << 16);
}

__global__ void k0_prep(const float* __restrict__ cb, char* __restrict__ ws) {
#pragma clang fp contract(off)
    int k = threadIdx.x;
    if (k >= KCODES) return;
    const float* cr = cb + (size_t)k * CDIM;
    // reference-order ||c||^2 (numpy pairwise-8) for the exact refine pass
    float r[8];
    #pragma unroll
    for (int j = 0; j < 8; ++j) r[j] = cr[j] * cr[j];
    #pragma unroll
    for (int t = 1; t < 8; ++t)
        #pragma unroll
        for (int j = 0; j < 8; ++j) r[j] += cr[8 * t + j] * cr[8 * t + j];
    ((float*)(ws + WS_C2REF))[k] = ((r[0] + r[1]) + (r[2] + r[3])) + ((r[4] + r[5]) + (r[6] + r[7]));
    // accurate ||c||^2 + bias, pre-scaled to fixed-point units
    float acc = 0.f;
    #pragma unroll
    for (int i = 0; i < CDIM; ++i) acc = fmaf(cr[i], cr[i], acc);
    ((float*)(ws + WS_C2FIX))[k] = (acc + BIAS) * SCALE;
    // bf16 codebook split, scaled by 2^11; k-major 16B chunks: chunk = g*512 + k
    unsigned short* hi = (unsigned short*)(ws + WS_CBHI);
    unsigned short* lo = (unsigned short*)(ws + WS_CBLO);
    #pragma unroll
    for (int g = 0; g < 8; ++g)
        #pragma unroll
        for (int j = 0; j < 8; ++j) {
            float cs = cr[g * 8 + j] * 2048.0f;
            uint32_t uh = f2bf_rne(cs);
            float l = cs - bf2f((short)uh);
            size_t o = ((size_t)(g * KCODES + k)) * 8 + j;
            hi[o] = (unsigned short)uh;
            lo[o] = (unsigned short)f2bf_rne(l);
        }
}

__global__ __launch_bounds__(256, 2) void k1_mfma(const float* __restrict__ z_e,
                                                  const float* __restrict__ cb,
                                                  char* __restrict__ ws,
                                                  float* __restrict__ out,
                                                  uint32_t stash_cap) {
    extern __shared__ char smem[];   // 65536 B cb_hi chunks + 2048 B c2fix
    const int tid  = threadIdx.x;
    const int lane = tid & 63;
    const int wave = tid >> 6;
    const int h    = lane >> 5;      // k-half selector
    const int c    = lane & 31;      // column (pixel/code) within 32

    {   // stage cb_hi (64KB) + c2fix (2KB) to LDS
        const uint4* src = (const uint4*)(ws + WS_CBHI);
        uint4* dst = (uint4*)smem;
        #pragma unroll
        for (int i = 0; i < 16; ++i)
            dst[i * 256 + tid] = src[i * 256 + tid];
        if (tid < 128)
            ((uint4*)(smem + 65536))[tid] = ((const uint4*)(ws + WS_C2FIX))[tid];
    }
    __syncthreads();

    const int gwave  = blockIdx.x * 4 + wave;
    const int pbase  = gwave * 64;          // 64 pixels per wave
    const int b      = pbase >> 12;
    const int hwbase = pbase & 4095;
    const float* zb  = z_e + (size_t)b * B_STRIDE;

    // B fragments: Z = -4096*z split hi/lo (scaled bf16); col=lane&31, k=(lane>>5)*8+j
    short8v zh[2][4], zl[2][4];
    #pragma unroll
    for (int t = 0; t < 2; ++t) {
        int hw = hwbase + t * 32 + c;
        #pragma unroll
        for (int s = 0; s < 4; ++s) {
            int ch0 = s * 16 + h * 8;
            short8v vh, vl;
            #pragma unroll
            for (int j = 0; j < 8; ++j) {
                float zs = zb[(size_t)(ch0 + j) * CH_STRIDE + hw] * -4096.0f;
                uint32_t uh = f2bf_rne(zs);
                float l = zs - bf2f((short)uh);
                vh[j] = (short)uh;
                vl[j] = (short)f2bf_rne(l);
            }
            zh[t][s] = vh; zl[t][s] = vl;
        }
    }

    const short8v* lo_chunks = (const short8v*)(ws + WS_CBLO);
    const float* c2f = (const float*)(smem + 65536);
    uint32_t m1[2] = {0xFFFFFFFFu, 0xFFFFFFFFu};
    uint32_t m2[2] = {0xFFFFFFFFu, 0xFFFFFFFFu};

    for (int t = 0; t < 16; ++t) {          // 16 code tiles of 32
        short8v a[4], al[4];
        #pragma unroll
        for (int s = 0; s < 4; ++s) {
            int chunk = (2 * s + h) * KCODES + t * 32 + c;
            a[s]  = *(const short8v*)(smem + (size_t)chunk * 16);
            al[s] = lo_chunks[chunk];
        }
        int rbase = t * 32 + 4 * h;
        f32x4 q0 = *(const f32x4*)(c2f + rbase + 0);
        f32x4 q1 = *(const f32x4*)(c2f + rbase + 8);
        f32x4 q2 = *(const f32x4*)(c2f + rbase + 16);
        f32x4 q3 = *(const f32x4*)(c2f + rbase + 24);

        #pragma unroll
        for (int set = 0; set < 2; ++set) {
            f32x16 acc;
            #pragma unroll
            for (int i = 0; i < 4; ++i) {
                acc[i] = q0[i]; acc[4 + i] = q1[i]; acc[8 + i] = q2[i]; acc[12 + i] = q3[i];
            }
            #pragma unroll
            for (int s = 0; s < 4; ++s)
                acc = __builtin_amdgcn_mfma_f32_32x32x16_bf16(a[s], zh[set][s], acc, 0, 0, 0);
            #pragma unroll
            for (int s = 0; s < 4; ++s)
                acc = __builtin_amdgcn_mfma_f32_32x32x16_bf16(a[s], zl[set][s], acc, 0, 0, 0);
            #pragma unroll
            for (int s = 0; s < 4; ++s)
                acc = __builtin_amdgcn_mfma_f32_32x32x16_bf16(al[s], zh[set][s], acc, 0, 0, 0);
            // fixed-point pack: u = ((uint)score_fixed << 9) | code ; min-track m1,m2
            #pragma unroll
            for (int i = 0; i < 16; ++i) {
                uint32_t code = (uint32_t)(t * 32 + 4 * h + (i & 3) + 8 * (i >> 2));
                uint32_t u = (((uint32_t)acc[i]) << 9) | code;
                uint32_t mx = m1[set] > u ? m1[set] : u;
                m2[set] = m2[set] < mx ? m2[set] : mx;
                m1[set] = m1[set] < u ? m1[set] : u;
            }
        }
    }

    // merge lanes l and l^32 (same pixel column)
    #pragma unroll
    for (int set = 0; set < 2; ++set) {
        uint32_t o1 = (uint32_t)__shfl_xor((int)m1[set], 32);
        uint32_t o2 = (uint32_t)__shfl_xor((int)m2[set], 32);
        uint32_t mx  = m1[set] > o1 ? m1[set] : o1;
        uint32_t mn2 = m2[set] < o2 ? m2[set] : o2;
        m2[set] = mn2 < mx ? mn2 : mx;
        m1[set] = m1[set] < o1 ? m1[set] : o1;
    }

    int  idxv[2]; bool flag[2];
    #pragma unroll
    for (int set = 0; set < 2; ++set) {
        idxv[set] = (int)(m1[set] & 0x1FFu);
        int gap = (int)((m2[set] >> 9) - (m1[set] >> 9));
        flag[set] = gap < MARGIN_UNITS;
    }

    // idx output: lane (h,c) owns pixel of set h, column c
    out[IDXOUT_OFF + pbase + h * 32 + c] = (float)(h ? idxv[1] : idxv[0]);

    // flagged pixels: record + stash exact z compactly (re-read is L2-hot)
    uint32_t* cntp = (uint32_t*)(ws + 8);
    uint32_t* flagged_arr = (uint32_t*)(ws + WS_FLAG);
    float* zstash = (float*)(ws + WS_ZSTASH);
    #pragma unroll
    for (int t = 0; t < 2; ++t) {
        if (flag[t]) {
            uint32_t slot = 0;
            if (h == t) slot = atomicAdd(cntp, 1u);
            slot = (uint32_t)__shfl((int)slot, t * 32 + c);   // broadcast from owner lane
            if (h == t) flagged_arr[slot] = (uint32_t)(pbase + t * 32 + c);
            if (slot < stash_cap) {
                float* zs = zstash + (size_t)slot * 64;
                int hw = hwbase + t * 32 + c;
                #pragma unroll
                for (int s = 0; s < 4; ++s)
                    #pragma unroll
                    for (int j = 0; j < 8; ++j) {
                        int ch = s * 16 + h * 8 + j;
                        zs[ch] = zb[(size_t)ch * CH_STRIDE + hw];
                    }
            }
        }
    }

    // fused z_q gather + write + loss for ALL pixels (refine fixes the changed few)
    float lsum = 0.f;
    #pragma unroll
    for (int set = 0; set < 2; ++set) {
        int hw = hwbase + set * 32 + c;
        const float* crow = cb + (size_t)idxv[set] * CDIM;
        float* ob = out + (size_t)b * B_STRIDE + hw;
        #pragma unroll
        for (int s = 0; s < 4; ++s) {
            int ch0 = s * 16 + h * 8;
            f32x4 g0 = *(const f32x4*)(crow + ch0);
            f32x4 g1 = *(const f32x4*)(crow + ch0 + 4);
            #pragma unroll
            for (int j = 0; j < 8; ++j) {
                float zq = (j < 4) ? g0[j] : g1[j - 4];
                float zv = (bf2f(zh[set][s][j]) + bf2f(zl[set][s][j])) * -2.44140625e-4f;
                ob[(size_t)(ch0 + j) * CH_STRIDE] = zq;
                float d = zq - zv;
                lsum = fmaf(d, d, lsum);
            }
        }
    }
    double dl = (double)lsum;
    for (int off = 32; off; off >>= 1) dl += __shfl_down(dl, off);
    if (lane == 0) atomicAdd((double*)ws, dl);
}

// exact reference-arithmetic re-resolution for flagged pixels (Round-2-verified math).
// z comes from the compact stash (identical exact f32 values); only CHANGED pixels
// get their idx/z_q rewritten and a loss delta applied.
__global__ void k2_refine(const float* __restrict__ z_e,
                          const float* __restrict__ cb,
                          char* __restrict__ ws,
                          float* __restrict__ out,
                          uint32_t stash_cap) {
#pragma clang fp contract(off)
    const uint32_t n = *(const volatile uint32_t*)(ws + 8);
    const float* c2r = (const float*)(ws + WS_C2REF);
    const uint32_t* flagged = (const uint32_t*)(ws + WS_FLAG);
    const float* zstash = (const float*)(ws + WS_ZSTASH);
    int gwave  = (blockIdx.x * blockDim.x + threadIdx.x) >> 6;
    int lane   = threadIdx.x & 63;
    int nwaves = (gridDim.x * blockDim.x) >> 6;

    for (uint32_t f = gwave; f < n; f += nwaves) {
        int p  = (int)flagged[f];
        int bb = p >> 12, hw = p & 4095;
        const float* zb = z_e + (size_t)bb * B_STRIDE + hw;
        float z[CDIM];
        if (f < stash_cap) {
            const float* zs = zstash + (size_t)f * 64;
            #pragma unroll
            for (int i = 0; i < CDIM; ++i) z[i] = zs[i];       // coalesced/broadcast, L2-hot
        } else {
            #pragma unroll
            for (int i = 0; i < CDIM; ++i) z[i] = zb[(size_t)i * CH_STRIDE];
        }
        float r[8];
        #pragma unroll
        for (int j = 0; j < 8; ++j) r[j] = z[j] * z[j];
        #pragma unroll
        for (int t = 1; t < 8; ++t)
            #pragma unroll
            for (int j = 0; j < 8; ++j) r[j] += z[8 * t + j] * z[8 * t + j];
        float A = ((r[0] + r[1]) + (r[2] + r[3])) + ((r[4] + r[5]) + (r[6] + r[7]));

        float best = 3.4e38f; int bidx = 0x7FFFFFFF;
        #pragma unroll
        for (int j = 0; j < 8; ++j) {
            int k = lane * 8 + j;
            const float* cr = cb + (size_t)k * CDIM;
            float a = 0.f;
            #pragma unroll
            for (int i = 0; i < CDIM; ++i) a = fmaf(z[i], cr[i], a);
            float d = (A - 2.0f * a) + c2r[k];
            if (d < best) { best = d; bidx = k; }
        }
        for (int off = 32; off; off >>= 1) {
            float ob = __shfl_down(best, off);
            int   oi = __shfl_down(bidx, off);
            if (ob < best || (ob == best && oi < bidx)) { best = ob; bidx = oi; }
        }
        bidx = __shfl(bidx, 0);
        int oldidx = (int)out[IDXOUT_OFF + p];
        if (bidx != oldidx) {
            if (lane == 0) out[IDXOUT_OFF + p] = (float)bidx;
            float zi = z[lane];
            float zq_new = cb[(size_t)bidx * CDIM + lane];
            float zq_old = cb[(size_t)oldidx * CDIM + lane];
            out[(size_t)bb * B_STRIDE + (size_t)lane * CH_STRIDE + hw] = zq_new;
            float dn = zq_new - zi, dold = zq_old - zi;
            double dl = (double)dn * dn - (double)dold * dold;
            for (int off = 32; off; off >>= 1) dl += __shfl_down(dl, off);
            if (lane == 0) atomicAdd((double*)ws, dl);
        }
    }
}

__global__ void k4_loss(float* __restrict__ out, const double* __restrict__ loss_acc) {
    out[LOSS_OFF] = (float)(1.25 * (*loss_acc) / (double)ZQ_SIZE);
}

extern "C" void kernel_launch(void* const* d_in, const int* in_sizes, int n_in,
                              void* d_out, int out_size, void* d_ws, size_t ws_size,
                              hipStream_t stream) {
    const float* z_e = (const float*)d_in[0];
    const float* cb  = (const float*)d_in[1];
    float* out = (float*)d_out;
    char* ws = (char*)d_ws;

    uint32_t cap = 0;
    if (ws_size > (size_t)WS_ZSTASH + 256)
        cap = (uint32_t)((ws_size - WS_ZSTASH) / 256);
    if (cap > NPIX) cap = NPIX;

    hipMemsetAsync(d_ws, 0, 64, stream);
    k0_prep<<<1, 512, 0, stream>>>(cb, ws);
    k1_mfma<<<NPIX / 256, 256, 67584, stream>>>(z_e, cb, ws, out, cap);
    k2_refine<<<512, 256, 0, stream>>>(z_e, cb, ws, out, cap);
    k4_loss<<<1, 1, 0, stream>>>(out, (const double*)ws);
}

// Round 8
// 182.136 us; speedup vs baseline: 3.0637x; 1.1110x over previous
//
#include <hip/hip_runtime.h>
#include <hip/hip_bf16.h>
#include <stdint.h>

// z_e (32,64,64,64) f32, codebook (512,64) f32.
// d_out (f32): [0..8388607] z_q (B,C,H,W); [8388608] loss; [8388609..] indices as float.
#define NPIX 131072
#define CDIM 64
#define KCODES 512
#define ZQ_SIZE 8388608
#define LOSS_OFF 8388608
#define IDXOUT_OFF 8388609
#define CH_STRIDE 4096
#define B_STRIDE 262144
#define MARGIN_UNITS 256       // 256 * 2^-22 ~ 6.1e-5 score gap: covers ref f32 grid noise
#define SCALE 4194304.0f       // 2^22
#define BIAS 0.5f

typedef __attribute__((ext_vector_type(8))) short short8v;   // 8 bf16
typedef __attribute__((ext_vector_type(16))) float f32x16;
typedef __attribute__((ext_vector_type(4))) float f32x4;

// ws layout:
//   0       double loss
//   64      float  c2_ref[512]   (numpy pairwise-8 order, for exact resolve)
//   2112    float  c2fix[512]    ((||c||^2 + 0.5) * 2^22)
//   4160    ushort cb_hi chunks  [g=0..7][code][8 bf16], scaled 2^11  (65536 B)
//   69696   ushort cb_lo chunks  same layout, residual scaled 2^11    (65536 B)
// total 135232 B — small, no ws_size risk.
#define WS_C2REF 64
#define WS_C2FIX 2112
#define WS_CBHI  4160
#define WS_CBLO  69696

__device__ __forceinline__ uint32_t f2bf_rne(float v) {
    uint32_t u = __float_as_uint(v);
    return (u + 0x7FFFu + ((u >> 16) & 1u)) >> 16;
}
__device__ __forceinline__ float bf2f(short s) {
    return __uint_as_float(((uint32_t)(unsigned short)s) << 16);
}

__global__ void k0_prep(const float* __restrict__ cb, char* __restrict__ ws) {
#pragma clang fp contract(off)
    int k = threadIdx.x;
    if (k >= KCODES) return;
    const float* cr = cb + (size_t)k * CDIM;
    // reference-order ||c||^2 (numpy pairwise-8) for the exact resolve
    float r[8];
    #pragma unroll
    for (int j = 0; j < 8; ++j) r[j] = cr[j] * cr[j];
    #pragma unroll
    for (int t = 1; t < 8; ++t)
        #pragma unroll
        for (int j = 0; j < 8; ++j) r[j] += cr[8 * t + j] * cr[8 * t + j];
    ((float*)(ws + WS_C2REF))[k] = ((r[0] + r[1]) + (r[2] + r[3])) + ((r[4] + r[5]) + (r[6] + r[7]));
    // accurate ||c||^2 + bias, pre-scaled to fixed-point units
    float acc = 0.f;
    #pragma unroll
    for (int i = 0; i < CDIM; ++i) acc = fmaf(cr[i], cr[i], acc);
    ((float*)(ws + WS_C2FIX))[k] = (acc + BIAS) * SCALE;
    // bf16 codebook split, scaled by 2^11; k-major 16B chunks: chunk = g*512 + k
    unsigned short* hi = (unsigned short*)(ws + WS_CBHI);
    unsigned short* lo = (unsigned short*)(ws + WS_CBLO);
    #pragma unroll
    for (int g = 0; g < 8; ++g)
        #pragma unroll
        for (int j = 0; j < 8; ++j) {
            float cs = cr[g * 8 + j] * 2048.0f;
            uint32_t uh = f2bf_rne(cs);
            float l = cs - bf2f((short)uh);
            size_t o = ((size_t)(g * KCODES + k)) * 8 + j;
            hi[o] = (unsigned short)uh;
            lo[o] = (unsigned short)f2bf_rne(l);
        }
}

__global__ __launch_bounds__(256, 2) void k1_mfma(const float* __restrict__ z_e,
                                                  const float* __restrict__ cb,
                                                  char* __restrict__ ws,
                                                  float* __restrict__ out) {
#pragma clang fp contract(off)
    extern __shared__ char smem[];   // 65536 B cb_hi chunks + 2048 B c2fix
    const int tid  = threadIdx.x;
    const int lane = tid & 63;
    const int wave = tid >> 6;
    const int h    = lane >> 5;      // k-half selector
    const int c    = lane & 31;      // column (pixel/code) within 32

    {   // stage cb_hi (64KB) + c2fix (2KB) to LDS
        const uint4* src = (const uint4*)(ws + WS_CBHI);
        uint4* dst = (uint4*)smem;
        #pragma unroll
        for (int i = 0; i < 16; ++i)
            dst[i * 256 + tid] = src[i * 256 + tid];
        if (tid < 128)
            ((uint4*)(smem + 65536))[tid] = ((const uint4*)(ws + WS_C2FIX))[tid];
    }
    __syncthreads();

    const int gwave  = blockIdx.x * 4 + wave;
    const int pbase  = gwave * 64;          // 64 pixels per wave
    const int b      = pbase >> 12;
    const int hwbase = pbase & 4095;
    const float* zb  = z_e + (size_t)b * B_STRIDE;

    // B fragments: Z = -4096*z split hi/lo (scaled bf16); col=lane&31, k=(lane>>5)*8+j
    short8v zh[2][4], zl[2][4];
    #pragma unroll
    for (int t = 0; t < 2; ++t) {
        int hw = hwbase + t * 32 + c;
        #pragma unroll
        for (int s = 0; s < 4; ++s) {
            int ch0 = s * 16 + h * 8;
            short8v vh, vl;
            #pragma unroll
            for (int j = 0; j < 8; ++j) {
                float zs = zb[(size_t)(ch0 + j) * CH_STRIDE + hw] * -4096.0f;
                uint32_t uh = f2bf_rne(zs);
                float l = zs - bf2f((short)uh);
                vh[j] = (short)uh;
                vl[j] = (short)f2bf_rne(l);
            }
            zh[t][s] = vh; zl[t][s] = vl;
        }
    }

    const short8v* lo_chunks = (const short8v*)(ws + WS_CBLO);
    const float* c2f = (const float*)(smem + 65536);
    uint32_t m1[2] = {0xFFFFFFFFu, 0xFFFFFFFFu};
    uint32_t m2[2] = {0xFFFFFFFFu, 0xFFFFFFFFu};

    for (int t = 0; t < 16; ++t) {          // 16 code tiles of 32
        short8v a[4], al[4];
        #pragma unroll
        for (int s = 0; s < 4; ++s) {
            int chunk = (2 * s + h) * KCODES + t * 32 + c;
            a[s]  = *(const short8v*)(smem + (size_t)chunk * 16);
            al[s] = lo_chunks[chunk];
        }
        int rbase = t * 32 + 4 * h;
        f32x4 q0 = *(const f32x4*)(c2f + rbase + 0);
        f32x4 q1 = *(const f32x4*)(c2f + rbase + 8);
        f32x4 q2 = *(const f32x4*)(c2f + rbase + 16);
        f32x4 q3 = *(const f32x4*)(c2f + rbase + 24);

        #pragma unroll
        for (int set = 0; set < 2; ++set) {
            f32x16 acc;
            #pragma unroll
            for (int i = 0; i < 4; ++i) {
                acc[i] = q0[i]; acc[4 + i] = q1[i]; acc[8 + i] = q2[i]; acc[12 + i] = q3[i];
            }
            #pragma unroll
            for (int s = 0; s < 4; ++s)
                acc = __builtin_amdgcn_mfma_f32_32x32x16_bf16(a[s], zh[set][s], acc, 0, 0, 0);
            #pragma unroll
            for (int s = 0; s < 4; ++s)
                acc = __builtin_amdgcn_mfma_f32_32x32x16_bf16(a[s], zl[set][s], acc, 0, 0, 0);
            #pragma unroll
            for (int s = 0; s < 4; ++s)
                acc = __builtin_amdgcn_mfma_f32_32x32x16_bf16(al[s], zh[set][s], acc, 0, 0, 0);
            // fixed-point pack: u = ((uint)score_fixed << 9) | code ; min-track m1,m2
            #pragma unroll
            for (int i = 0; i < 16; ++i) {
                uint32_t code = (uint32_t)(t * 32 + 4 * h + (i & 3) + 8 * (i >> 2));
                uint32_t u = (((uint32_t)acc[i]) << 9) | code;
                uint32_t mx = m1[set] > u ? m1[set] : u;
                m2[set] = m2[set] < mx ? m2[set] : mx;
                m1[set] = m1[set] < u ? m1[set] : u;
            }
        }
    }

    // merge lanes l and l^32 (same pixel column)
    #pragma unroll
    for (int set = 0; set < 2; ++set) {
        uint32_t o1 = (uint32_t)__shfl_xor((int)m1[set], 32);
        uint32_t o2 = (uint32_t)__shfl_xor((int)m2[set], 32);
        uint32_t mx  = m1[set] > o1 ? m1[set] : o1;
        uint32_t mn2 = m2[set] < o2 ? m2[set] : o2;
        m2[set] = mn2 < mx ? mn2 : mx;
        m1[set] = m1[set] < o1 ? m1[set] : o1;
    }

    int  idxv[2]; bool flag[2];
    #pragma unroll
    for (int set = 0; set < 2; ++set) {
        idxv[set] = (int)(m1[set] & 0x1FFu);
        int gap = (int)((m2[set] >> 9) - (m1[set] >> 9));
        flag[set] = gap < MARGIN_UNITS;
    }

    // -------- in-wave exact resolve for near-tie columns (reference f32 math) -----
    // Wave-collective: one flagged pixel at a time. Lane l supplies z[l]; each lane
    // evaluates its 8 codes (exact f32 codebook from L2) with Round-2-verified
    // arithmetic: pairwise-8 ||z||^2, sequential ascending fmaf dot, (A-2a)+c2_ref,
    // first-index tie-break.
    {
        const float* c2r = (const float*)(ws + WS_C2REF);
        #pragma unroll 1
        for (int set = 0; set < 2; ++set) {
            unsigned long long mask = __ballot(flag[set]) & 0xFFFFFFFFull;
            #pragma unroll 1
            while (mask) {
                int col = (int)__builtin_ctzll(mask);
                mask &= mask - 1;
                int hw = hwbase + set * 32 + col;          // wave-uniform
                float zme = zb[(size_t)lane * CH_STRIDE + hw];   // lane l = channel l
                const float* crp = cb + (size_t)(lane * 8) * CDIM;
                float a[8] = {0.f,0.f,0.f,0.f,0.f,0.f,0.f,0.f};
                float r[8] = {0.f,0.f,0.f,0.f,0.f,0.f,0.f,0.f};
                for (int i = 0; i < CDIM; ++i) {
                    float zi = __shfl(zme, i);
                    r[i & 7] += zi * zi;                   // 0+round(z*z) == ref first step
                    #pragma unroll
                    for (int k = 0; k < 8; ++k)
                        a[k] = fmaf(zi, crp[(size_t)k * CDIM + i], a[k]);
                }
                float A = ((r[0] + r[1]) + (r[2] + r[3])) + ((r[4] + r[5]) + (r[6] + r[7]));
                float best = 3.4e38f; int bidx = 0x7FFFFFFF;
                #pragma unroll
                for (int k = 0; k < 8; ++k) {
                    float d = (A - 2.0f * a[k]) + c2r[lane * 8 + k];
                    if (d < best) { best = d; bidx = lane * 8 + k; }
                }
                for (int off = 32; off; off >>= 1) {
                    float ob = __shfl_down(best, off);
                    int   oi = __shfl_down(bidx, off);
                    if (ob < best || (ob == best && oi < bidx)) { best = ob; bidx = oi; }
                }
                bidx = __shfl(bidx, 0);
                if (c == col) idxv[set] = bidx;            // both h-halves of the column
            }
        }
    }

    // idx output: lane (h,c) owns pixel of set h, column c
    out[IDXOUT_OFF + pbase + h * 32 + c] = (float)(h ? idxv[1] : idxv[0]);

    // fused z_q gather + write + loss for ALL pixels (indices already final)
    float lsum = 0.f;
    #pragma unroll
    for (int set = 0; set < 2; ++set) {
        int hw = hwbase + set * 32 + c;
        const float* crow = cb + (size_t)idxv[set] * CDIM;
        float* ob = out + (size_t)b * B_STRIDE + hw;
        #pragma unroll
        for (int s = 0; s < 4; ++s) {
            int ch0 = s * 16 + h * 8;
            f32x4 g0 = *(const f32x4*)(crow + ch0);
            f32x4 g1 = *(const f32x4*)(crow + ch0 + 4);
            #pragma unroll
            for (int j = 0; j < 8; ++j) {
                float zq = (j < 4) ? g0[j] : g1[j - 4];
                float zv = (bf2f(zh[set][s][j]) + bf2f(zl[set][s][j])) * -2.44140625e-4f;
                ob[(size_t)(ch0 + j) * CH_STRIDE] = zq;
                float d = zq - zv;
                lsum = fmaf(d, d, lsum);
            }
        }
    }
    double dl = (double)lsum;
    for (int off = 32; off; off >>= 1) dl += __shfl_down(dl, off);
    if (lane == 0) atomicAdd((double*)ws, dl);
}

__global__ void k4_loss(float* __restrict__ out, const double* __restrict__ loss_acc) {
    out[LOSS_OFF] = (float)(1.25 * (*loss_acc) / (double)ZQ_SIZE);
}

extern "C" void kernel_launch(void* const* d_in, const int* in_sizes, int n_in,
                              void* d_out, int out_size, void* d_ws, size_t ws_size,
                              hipStream_t stream) {
    const float* z_e = (const float*)d_in[0];
    const float* cb  = (const float*)d_in[1];
    float* out = (float*)d_out;
    char* ws = (char*)d_ws;

    hipMemsetAsync(d_ws, 0, 64, stream);
    k0_prep<<<1, 512, 0, stream>>>(cb, ws);
    k1_mfma<<<NPIX / 256, 256, 67584, stream>>>(z_e, cb, ws, out);
    k4_loss<<<1, 1, 0, stream>>>(out, (const double*)ws);
}